// Round 3
// baseline (318.441 us; speedup 1.0000x reference)
//
#include <hip/hip_runtime.h>
#include <stdint.h>

#define BATCH 16
#define CH    256
#define NSP   4096   // 64*64 spatial
#define NH    4
#define HD    64

typedef __attribute__((ext_vector_type(8))) short bf16x8;
typedef __attribute__((ext_vector_type(4))) float f32x4;
typedef __attribute__((ext_vector_type(4))) unsigned int u32x4;

__device__ __forceinline__ short f2bf(float f) {
    union { float f; unsigned u; } v; v.f = f;
    unsigned r = (v.u + 0x7fffu + ((v.u >> 16) & 1u)) >> 16;
    return (short)r;
}
__device__ __forceinline__ float bf2f(short s) {
    union { float f; unsigned u; } v; v.u = ((unsigned)(unsigned short)s) << 16;
    return v.f;
}

// ---------------- weight fp32 -> bf16 ----------------
__global__ __launch_bounds__(256) void k_convert_w(
        const float* __restrict__ wq, const float* __restrict__ wo,
        short* __restrict__ wq_bf, short* __restrict__ wo_bf) {
    int i = blockIdx.x * 256 + threadIdx.x;
    if (i < 768 * 256) wq_bf[i] = f2bf(wq[i]);
    if (i < 256 * 256) wo_bf[i] = f2bf(wo[i]);
}

// ---------------- GroupNorm stats: one block per (b,g), 8ch*4096 contiguous ----------------
__global__ __launch_bounds__(256) void k_gn_stats(
        const float* __restrict__ x, float* __restrict__ mu, float* __restrict__ rstd) {
    int bg = blockIdx.x; // 0..511
    const float4* p = (const float4*)(x + (size_t)bg * 32768);
    float s = 0.f, sq = 0.f;
    for (int i = threadIdx.x; i < 8192; i += 256) {
        float4 v = p[i];
        s  += v.x + v.y + v.z + v.w;
        sq += v.x * v.x + v.y * v.y + v.z * v.z + v.w * v.w;
    }
    for (int off = 32; off; off >>= 1) { s += __shfl_down(s, off); sq += __shfl_down(sq, off); }
    __shared__ float ls[4], lq[4];
    int w = threadIdx.x >> 6;
    if ((threadIdx.x & 63) == 0) { ls[w] = s; lq[w] = sq; }
    __syncthreads();
    if (threadIdx.x == 0) {
        float S = ls[0] + ls[1] + ls[2] + ls[3];
        float Q = lq[0] + lq[1] + lq[2] + lq[3];
        float m = S / 32768.f;
        float var = Q / 32768.f - m * m;
        mu[bg] = m; rstd[bg] = rsqrtf(var + 1e-5f);
    }
}

// ---------------- GN apply + transpose: write xn_t[b][n][c] bf16 ----------------
__global__ __launch_bounds__(256) void k_gn_apply(
        const float* __restrict__ x, const float* __restrict__ gamma,
        const float* __restrict__ beta, const float* __restrict__ mu,
        const float* __restrict__ rstd, short* __restrict__ xn_t) {
    int b = blockIdx.y;
    int n0 = blockIdx.x * 64;
    __shared__ short lds[64 * 264];
    __shared__ float smu[32], srstd[32], sg[256], sb[256];
    int t = threadIdx.x;
    if (t < 32) { smu[t] = mu[b * 32 + t]; srstd[t] = rstd[b * 32 + t]; }
    sg[t] = gamma[t]; sb[t] = beta[t];
    __syncthreads();
    int nl4 = (t & 15) * 4, cq = t >> 4; // 16 channels per iter, float4 per thread
    const float* xb = x + (size_t)b * CH * NSP;
    for (int cb = 0; cb < 16; cb++) {
        int c = cb * 16 + cq;
        int g = c >> 3;
        float4 v = *(const float4*)(xb + (size_t)c * NSP + n0 + nl4);
        float sc = srstd[g] * sg[c];
        float sh = sb[c] - smu[g] * sc;
        lds[(nl4 + 0) * 264 + c] = f2bf(v.x * sc + sh);
        lds[(nl4 + 1) * 264 + c] = f2bf(v.y * sc + sh);
        lds[(nl4 + 2) * 264 + c] = f2bf(v.z * sc + sh);
        lds[(nl4 + 3) * 264 + c] = f2bf(v.w * sc + sh);
    }
    __syncthreads();
    short* outb = xn_t + ((size_t)b * NSP + n0) * CH;
    #pragma unroll
    for (int i = 0; i < 8; i++) {
        int ch = t + i * 256;          // 2048 chunks of 8
        int row = ch >> 5, cc = (ch & 31) * 8;
        *(u32x4*)(outb + (size_t)row * CH + cc) = *(const u32x4*)(lds + row * 264 + cc);
    }
}

// ---------------- QKV GEMM + fused kv^T partials ----------------
// mt 0-1: q rows (elu+1) -> q_t[b][h][n][d]
// mt 2-5: head h=mt-2: rows 0..63 = k_h (elu+1), rows 64..127 = v_h.
//         second MFMA pass: kvp[bh][nt][e][d] = v·k^T over this n-tile (private, no atomics),
//         ksp[bh][nt][d] = sum_n k.
__global__ __launch_bounds__(256) void k_qkv_gemm(
        const short* __restrict__ wq_bf, const float* __restrict__ b_qkv,
        const short* __restrict__ xn_t, short* __restrict__ q_t,
        float* __restrict__ kvp, float* __restrict__ ksp) {
    int b = blockIdx.z, mt = blockIdx.y, nt = blockIdx.x;
    bool is_q = (mt < 2);
    int h = mt - 2;
    __shared__ union SM {
        struct { short a[128 * 40]; short bm[128 * 40]; } st;
        short c[128 * 136];
    } sm;
    __shared__ float ksred[64];
    int t = threadIdx.x, lane = t & 63, wv = t >> 6;
    int lr = lane & 15, quad = lane >> 4;
    int wm = (wv & 1) * 64, wn = (wv >> 1) * 64;
    f32x4 acc[4][4] = {};
    const short* Bb = xn_t + ((size_t)b * NSP + (size_t)nt * 128) * 256;
    // A-row global indices are k0-invariant: hoist
    int arow[2];
    #pragma unroll
    for (int i = 0; i < 2; i++) {
        int row = (t + i * 256) >> 2;
        arow[i] = is_q ? (mt * 128 + row)
                       : (row < 64 ? 256 + h * 64 + row : 512 + h * 64 + (row - 64));
    }
    for (int k0 = 0; k0 < 256; k0 += 32) {
        #pragma unroll
        for (int i = 0; i < 2; i++) {
            int ch = t + i * 256;
            int row = ch >> 2, kc = (ch & 3) * 8;
            *(u32x4*)(sm.st.a  + row * 40 + kc) = *(const u32x4*)(wq_bf + (size_t)arow[i] * 256 + k0 + kc);
            *(u32x4*)(sm.st.bm + row * 40 + kc) = *(const u32x4*)(Bb + (size_t)row * 256 + k0 + kc);
        }
        __syncthreads();
        bf16x8 afr[4], bfr[4];
        #pragma unroll
        for (int mi = 0; mi < 4; mi++) afr[mi] = *(const bf16x8*)(sm.st.a  + (wm + mi * 16 + lr) * 40 + quad * 8);
        #pragma unroll
        for (int ni = 0; ni < 4; ni++) bfr[ni] = *(const bf16x8*)(sm.st.bm + (wn + ni * 16 + lr) * 40 + quad * 8);
        #pragma unroll
        for (int mi = 0; mi < 4; mi++)
            #pragma unroll
            for (int ni = 0; ni < 4; ni++)
                acc[mi][ni] = __builtin_amdgcn_mfma_f32_16x16x32_bf16(afr[mi], bfr[ni], acc[mi][ni], 0, 0, 0);
        __syncthreads();
    }
    if (t < 64) ksred[t] = 0.f;
    #pragma unroll
    for (int mi = 0; mi < 4; mi++)
      #pragma unroll
      for (int ni = 0; ni < 4; ni++)
        #pragma unroll
        for (int r = 0; r < 4; r++) {
            int ol = wm + mi * 16 + quad * 4 + r;
            int nl = wn + ni * 16 + lr;
            int o = is_q ? (mt * 128 + ol)
                         : (ol < 64 ? 256 + h * 64 + ol : 512 + h * 64 + (ol - 64));
            float v = acc[mi][ni][r] + b_qkv[o];
            if (o < 512) v = v > 0.f ? v + 1.f : __expf(v);   // elu(x)+1
            if (is_q) sm.c[nl * 136 + ol] = f2bf(v);          // transposed staging [n][o]
            else      sm.c[ol * 136 + nl] = f2bf(v);          // natural staging [o][n]
        }
    __syncthreads();
    if (is_q) {
        short* qb = q_t + (size_t)b * NH * NSP * HD;
        #pragma unroll
        for (int i = 0; i < 8; i++) {
            int ch = t + i * 256;
            int row = ch >> 4, c8 = (ch & 15) * 8;
            int hh = mt * 2 + (c8 >> 6), d0 = c8 & 63;
            int n = nt * 128 + row;
            *(u32x4*)(qb + ((size_t)hh * NSP + n) * HD + d0) = *(const u32x4*)(sm.c + row * 136 + c8);
        }
    } else {
        // ksum partials: thread t sums k[d=t>>2][n-chunk (t&3)*32..+32] into LDS
        {
            int kd = t >> 2, nc0 = (t & 3) * 32;
            float s = 0.f;
            #pragma unroll
            for (int j = 0; j < 32; j++) s += bf2f(sm.c[kd * 136 + nc0 + j]);
            atomicAdd(&ksred[kd], s);
        }
        // kv^T pass: A = v rows (64..127) [e][n], B = k rows (0..63) [d][n], K=128.
        // Wave wv owns e-rows wv*16..wv*16+15 exclusively.
        f32x4 acc2[4] = {};
        #pragma unroll
        for (int kk = 0; kk < 128; kk += 32) {
            bf16x8 af = *(const bf16x8*)(sm.c + (64 + wv * 16 + lr) * 136 + kk + quad * 8);
            bf16x8 bf[4];
            #pragma unroll
            for (int ni = 0; ni < 4; ni++)
                bf[ni] = *(const bf16x8*)(sm.c + (ni * 16 + lr) * 136 + kk + quad * 8);
            #pragma unroll
            for (int ni = 0; ni < 4; ni++)
                acc2[ni] = __builtin_amdgcn_mfma_f32_16x16x32_bf16(af, bf[ni], acc2[ni], 0, 0, 0);
        }
        __syncthreads();   // ksred complete
        int bh = b * NH + h;
        // private partial slice: no contention, plain coalesced stores
        float* kvp_blk = kvp + ((size_t)bh * 32 + nt) * 4096;
        #pragma unroll
        for (int ni = 0; ni < 4; ni++)
            #pragma unroll
            for (int r = 0; r < 4; r++) {
                int e = wv * 16 + quad * 4 + r;
                int d = ni * 16 + lr;
                kvp_blk[e * 64 + d] = acc2[ni][r];
            }
        if (t < 64) ksp[((size_t)bh * 32 + nt) * 64 + t] = ksred[t];
    }
}

// ---------------- reduce kv partials: kvT_g[bh][e][d] = sum_nt kvp, ksum likewise ----------------
__global__ __launch_bounds__(256) void k_kv_reduce(
        const float* __restrict__ kvp, const float* __restrict__ ksp,
        float* __restrict__ kvT_g, float* __restrict__ ksum_g) {
    int bh = blockIdx.x;
    int t = threadIdx.x;
    const float4* base = (const float4*)(kvp + (size_t)bh * 32 * 4096);
    float4* outv = (float4*)(kvT_g + (size_t)bh * 4096);
    for (int i = t; i < 1024; i += 256) {
        float4 s = {0.f, 0.f, 0.f, 0.f};
        for (int ntc = 0; ntc < 32; ntc++) {
            float4 v = base[(size_t)ntc * 1024 + i];
            s.x += v.x; s.y += v.y; s.z += v.z; s.w += v.w;
        }
        outv[i] = s;
    }
    if (t < 64) {
        float s = 0.f;
        const float* kb = ksp + (size_t)bh * 32 * 64 + t;
        for (int ntc = 0; ntc < 32; ntc++) s += kb[ntc * 64];
        ksum_g[bh * 64 + t] = s;
    }
}

// ---------------- attn: outT[n][e] = q_t[n,:]·kv[:,e] / denom[n]; write attn_t[b][n][h*64+e] ----------------
__global__ __launch_bounds__(256) void k_attn(
        const short* __restrict__ q_t, const float* __restrict__ kvT_g,
        const float* __restrict__ ksum_g, short* __restrict__ attn_t) {
    int nt = blockIdx.x, h = blockIdx.y, b = blockIdx.z;
    int bh = b * 4 + h;
    __shared__ short ql[128 * 72];
    __shared__ short kvl[64 * 72];
    __shared__ float ksl[64];
    __shared__ float dnl[128];
    int t = threadIdx.x, lane = t & 63, wv = t >> 6, lr = lane & 15, quad = lane >> 4;
    const short* qb = q_t + ((size_t)bh * NSP + (size_t)nt * 128) * HD;
    #pragma unroll
    for (int i = 0; i < 4; i++) {
        int ch = t + i * 256;
        int row = ch >> 3, dc = (ch & 7) * 8;
        *(u32x4*)(ql + row * 72 + dc) = *(const u32x4*)(qb + (size_t)row * HD + dc);
    }
    const float* kvg = kvT_g + (size_t)bh * 4096;
    for (int i = t; i < 4096; i += 256)
        kvl[(i >> 6) * 72 + (i & 63)] = f2bf(kvg[i]);
    if (t < 64) ksl[t] = ksum_g[bh * 64 + t];
    __syncthreads();
    if (t < 128) {
        float s = 0.f;
        #pragma unroll
        for (int d = 0; d < 64; d++) s += bf2f(ql[t * 72 + d]) * ksl[d];
        dnl[t] = 1.f / (s + 1e-6f);
    }
    __syncthreads();
    f32x4 acc[2][4] = {};
    int mbase = wv * 32;
    #pragma unroll
    for (int kk = 0; kk < 64; kk += 32) {
        bf16x8 afr[2], bfr[4];
        #pragma unroll
        for (int mi = 0; mi < 2; mi++) afr[mi] = *(const bf16x8*)(ql + (mbase + mi * 16 + lr) * 72 + kk + quad * 8);
        #pragma unroll
        for (int ni = 0; ni < 4; ni++) bfr[ni] = *(const bf16x8*)(kvl + (ni * 16 + lr) * 72 + kk + quad * 8);
        #pragma unroll
        for (int mi = 0; mi < 2; mi++)
            #pragma unroll
            for (int ni = 0; ni < 4; ni++)
                acc[mi][ni] = __builtin_amdgcn_mfma_f32_16x16x32_bf16(afr[mi], bfr[ni], acc[mi][ni], 0, 0, 0);
    }
    short* ob = attn_t + ((size_t)b * NSP + (size_t)nt * 128) * CH + h * 64;
    #pragma unroll
    for (int mi = 0; mi < 2; mi++)
      #pragma unroll
      for (int ni = 0; ni < 4; ni++)
        #pragma unroll
        for (int r = 0; r < 4; r++) {
            int nl = mbase + mi * 16 + quad * 4 + r;
            int e = ni * 16 + lr;
            ob[(size_t)nl * CH + e] = f2bf(acc[mi][ni][r] * dnl[nl]);
        }
}

// ---------------- final: out[b,o,n] = Wout[o,:]·attn_t[n,:] + b_out[o] + x[b,o,n] ----------------
__global__ __launch_bounds__(256) void k_out_gemm(
        const short* __restrict__ wo_bf, const float* __restrict__ b_out,
        const short* __restrict__ attn_t, const float* __restrict__ x,
        float* __restrict__ out) {
    int b = blockIdx.z, mt = blockIdx.y, nt = blockIdx.x;
    __shared__ short lds_a[128 * 40];
    __shared__ short lds_b[128 * 40];
    int t = threadIdx.x, lane = t & 63, wv = t >> 6, lr = lane & 15, quad = lane >> 4;
    int wm = (wv & 1) * 64, wn = (wv >> 1) * 64;
    f32x4 acc[4][4] = {};
    const short* Ab = wo_bf + (size_t)mt * 128 * 256;
    const short* Bb = attn_t + ((size_t)b * NSP + (size_t)nt * 128) * 256;
    for (int k0 = 0; k0 < 256; k0 += 32) {
        #pragma unroll
        for (int i = 0; i < 2; i++) {
            int ch = t + i * 256;
            int row = ch >> 2, kc = (ch & 3) * 8;
            *(u32x4*)(lds_a + row * 40 + kc) = *(const u32x4*)(Ab + (size_t)row * 256 + k0 + kc);
            *(u32x4*)(lds_b + row * 40 + kc) = *(const u32x4*)(Bb + (size_t)row * 256 + k0 + kc);
        }
        __syncthreads();
        bf16x8 afr[4], bfr[4];
        #pragma unroll
        for (int mi = 0; mi < 4; mi++) afr[mi] = *(const bf16x8*)(lds_a + (wm + mi * 16 + lr) * 40 + quad * 8);
        #pragma unroll
        for (int ni = 0; ni < 4; ni++) bfr[ni] = *(const bf16x8*)(lds_b + (wn + ni * 16 + lr) * 40 + quad * 8);
        #pragma unroll
        for (int mi = 0; mi < 4; mi++)
            #pragma unroll
            for (int ni = 0; ni < 4; ni++)
                acc[mi][ni] = __builtin_amdgcn_mfma_f32_16x16x32_bf16(afr[mi], bfr[ni], acc[mi][ni], 0, 0, 0);
        __syncthreads();
    }
    const float* xb = x + ((size_t)b * CH + (size_t)mt * 128) * NSP + (size_t)nt * 128;
    float* outb = out + ((size_t)b * CH + (size_t)mt * 128) * NSP + (size_t)nt * 128;
    #pragma unroll
    for (int mi = 0; mi < 4; mi++)
      #pragma unroll
      for (int ni = 0; ni < 4; ni++)
        #pragma unroll
        for (int r = 0; r < 4; r++) {
            int ol = wm + mi * 16 + quad * 4 + r;
            int nl = wn + ni * 16 + lr;
            int o = mt * 128 + ol;
            outb[(size_t)ol * NSP + nl] = acc[mi][ni][r] + b_out[o] + xb[(size_t)ol * NSP + nl];
        }
}

extern "C" void kernel_launch(void* const* d_in, const int* in_sizes, int n_in,
                              void* d_out, int out_size, void* d_ws, size_t ws_size,
                              hipStream_t stream) {
    const float* x     = (const float*)d_in[0];
    const float* gamma = (const float*)d_in[1];
    const float* beta  = (const float*)d_in[2];
    const float* w_qkv = (const float*)d_in[3];
    const float* b_qkv = (const float*)d_in[4];
    const float* w_out = (const float*)d_in[5];
    const float* b_out = (const float*)d_in[6];
    float* out = (float*)d_out;

    char* ws = (char*)d_ws;
    size_t off = 0;
    float* mu    = (float*)(ws + off); off += 2048;
    float* rstd  = (float*)(ws + off); off += 2048;
    short* wq_bf = (short*)(ws + off); off += (size_t)768 * 256 * 2;
    short* wo_bf = (short*)(ws + off); off += (size_t)256 * 256 * 2;
    short* xn_t  = (short*)(ws + off);                    // [b][n][c] bf16
    short* attn_t = xn_t;                                 // aliased: xn_t dead after QKV GEMM
    off += (size_t)BATCH * NSP * CH * 2;
    short* q_t   = (short*)(ws + off); off += (size_t)BATCH * NSP * CH * 2;  // [b][h][n][d]
    float* kvp   = (float*)(ws + off); off += (size_t)64 * 32 * 4096 * 4;    // [bh][nt][e][d] partials
    float* ksp   = (float*)(ws + off); off += (size_t)64 * 32 * 64 * 4;      // [bh][nt][d] partials
    float* kvT_g = (float*)(ws + off); off += (size_t)64 * 4096 * 4;         // [bh][e][d]
    float* ksum_g = (float*)(ws + off); off += (size_t)64 * 64 * 4;          // [bh][d]

    if (ws_size < off) return;

    k_convert_w<<<768, 256, 0, stream>>>(w_qkv, w_out, wq_bf, wo_bf);
    k_gn_stats<<<512, 256, 0, stream>>>(x, mu, rstd);
    k_gn_apply<<<dim3(64, 16), 256, 0, stream>>>(x, gamma, beta, mu, rstd, xn_t);
    k_qkv_gemm<<<dim3(32, 6, 16), 256, 0, stream>>>(wq_bf, b_qkv, xn_t, q_t, kvp, ksp);
    k_kv_reduce<<<64, 256, 0, stream>>>(kvp, ksp, kvT_g, ksum_g);
    k_attn<<<dim3(32, 4, 16), 256, 0, stream>>>(q_t, kvT_g, ksum_g, attn_t);
    k_out_gemm<<<dim3(32, 2, 16), 256, 0, stream>>>(wo_bf, b_out, attn_t, x, out);
}

// Round 4
// 283.166 us; speedup vs baseline: 1.1246x; 1.1246x over previous
//
#include <hip/hip_runtime.h>
#include <stdint.h>

#define BATCH 16
#define CH    256
#define NSP   4096   // 64*64 spatial
#define NH    4
#define HD    64

typedef __attribute__((ext_vector_type(8))) short bf16x8;
typedef __attribute__((ext_vector_type(4))) float f32x4;
typedef __attribute__((ext_vector_type(4))) unsigned int u32x4;

__device__ __forceinline__ short f2bf(float f) {
    union { float f; unsigned u; } v; v.f = f;
    unsigned r = (v.u + 0x7fffu + ((v.u >> 16) & 1u)) >> 16;
    return (short)r;
}
__device__ __forceinline__ float bf2f(short s) {
    union { float f; unsigned u; } v; v.u = ((unsigned)(unsigned short)s) << 16;
    return v.f;
}

// ---------------- fused: GN stats (blocks 0..511) + weight bf16 convert (512..767) ----------------
__global__ __launch_bounds__(256) void k_pre(
        const float* __restrict__ x, const float* __restrict__ wq, const float* __restrict__ wo,
        float* __restrict__ mu, float* __restrict__ rstd,
        short* __restrict__ wq_bf, short* __restrict__ wo_bf) {
    int bg = blockIdx.x;
    if (bg < 512) {
        const float4* p = (const float4*)(x + (size_t)bg * 32768);
        float s = 0.f, sq = 0.f;
        for (int i = threadIdx.x; i < 8192; i += 256) {
            float4 v = p[i];
            s  += v.x + v.y + v.z + v.w;
            sq += v.x * v.x + v.y * v.y + v.z * v.z + v.w * v.w;
        }
        for (int off = 32; off; off >>= 1) { s += __shfl_down(s, off); sq += __shfl_down(sq, off); }
        __shared__ float ls[4], lq[4];
        int w = threadIdx.x >> 6;
        if ((threadIdx.x & 63) == 0) { ls[w] = s; lq[w] = sq; }
        __syncthreads();
        if (threadIdx.x == 0) {
            float S = ls[0] + ls[1] + ls[2] + ls[3];
            float Q = lq[0] + lq[1] + lq[2] + lq[3];
            float m = S / 32768.f;
            float var = Q / 32768.f - m * m;
            mu[bg] = m; rstd[bg] = rsqrtf(var + 1e-5f);
        }
    } else {
        int idx = ((bg - 512) * 256 + threadIdx.x) * 4;   // 0..262140, covers 196608 wq + 65536 wo
        float4 v;
        short* dst;
        if (idx < 196608) { v = *(const float4*)(wq + idx); dst = wq_bf + idx; }
        else              { v = *(const float4*)(wo + (idx - 196608)); dst = wo_bf + (idx - 196608); }
        unsigned p0 = ((unsigned)(unsigned short)f2bf(v.x)) | (((unsigned)(unsigned short)f2bf(v.y)) << 16);
        unsigned p1 = ((unsigned)(unsigned short)f2bf(v.z)) | (((unsigned)(unsigned short)f2bf(v.w)) << 16);
        uint2 pk; pk.x = p0; pk.y = p1;
        *(uint2*)dst = pk;
    }
}

// ---------------- fused GN-apply + QKV GEMM + kv^T partials + ksum partials + q_t ----------------
// One block per (b, 64-n tile). B tile (xn^T, [n][c]) built ONCE in LDS with GN applied,
// XOR-swizzled (chunk ^= ((n>>4)&3)<<3) to tame transpose-write bank conflicts.
// Then: per head h: k GEMM (elu) -> kst, ksum; v GEMM -> vst; kv MFMA -> kvp partial.
// Then: 2 q GEMMs (elu) -> LDS transpose -> q_t[b][h][n][d].
__global__ __launch_bounds__(256) void k_gnqkv(
        const float* __restrict__ x, const float* __restrict__ gamma, const float* __restrict__ beta,
        const float* __restrict__ mu, const float* __restrict__ rstd,
        const short* __restrict__ wq_bf, const float* __restrict__ b_qkv,
        short* __restrict__ q_t, float* __restrict__ kvp, float* __restrict__ ksp) {
    int b = blockIdx.y, nt = blockIdx.x;
    int n0 = nt * 64;
    __shared__ short Blds[64 * 264];          // [n][c^swz] bf16 xn tile
    __shared__ short Asm[128 * 40];           // A staging (weights)
    __shared__ union UR {
        struct { short kst[64 * 72]; short vst[64 * 72]; } s;   // k/v tiles [d|e][n]
        short cst[64 * 136];                                     // q transpose staging [n][o]
    } R;
    int t = threadIdx.x, lane = t & 63, wv = t >> 6, lr = lane & 15, quad = lane >> 4;

    // ---- build B tile with GN ----
    {
        const float* xb = x + (size_t)b * CH * NSP;
        int m = t & 15, cq = t >> 4;
        for (int cb = 0; cb < 16; cb++) {
            int c = cb * 16 + cq;
            int g = c >> 3;
            float sc = rstd[b * 32 + g] * gamma[c];
            float sh = beta[c] - mu[b * 32 + g] * sc;
            float4 v = *(const float4*)(xb + (size_t)c * NSP + n0 + m * 4);
            float vv[4] = {v.x, v.y, v.z, v.w};
            #pragma unroll
            for (int j = 0; j < 4; j++) {
                int n = m * 4 + j;
                int cc = c ^ (((n >> 4) & 3) << 3);
                Blds[n * 264 + cc] = f2bf(vv[j] * sc + sh);
            }
        }
    }
    __syncthreads();

    // ---- per-head k/v GEMMs + kv partial ----
    for (int h = 0; h < 4; h++) {
        for (int pass = 0; pass < 2; pass++) {
            int base = (pass ? 512 : 256) + h * 64;
            f32x4 acc[2][2] = {};
            int wm = (wv & 1) * 32, wn = (wv >> 1) * 32;
            for (int k0 = 0; k0 < 256; k0 += 32) {
                int row = t >> 2, kc = (t & 3) * 8;
                *(u32x4*)(Asm + row * 40 + kc) = *(const u32x4*)(wq_bf + (size_t)(base + row) * 256 + k0 + kc);
                __syncthreads();
                bf16x8 afr[2], bfr[2];
                #pragma unroll
                for (int mi = 0; mi < 2; mi++) afr[mi] = *(const bf16x8*)(Asm + (wm + mi * 16 + lr) * 40 + quad * 8);
                #pragma unroll
                for (int ni = 0; ni < 2; ni++) {
                    int rr = wn + ni * 16 + lr;
                    bfr[ni] = *(const bf16x8*)(Blds + rr * 264 + ((k0 + quad * 8) ^ (((rr >> 4) & 3) << 3)));
                }
                #pragma unroll
                for (int mi = 0; mi < 2; mi++)
                    #pragma unroll
                    for (int ni = 0; ni < 2; ni++)
                        acc[mi][ni] = __builtin_amdgcn_mfma_f32_16x16x32_bf16(afr[mi], bfr[ni], acc[mi][ni], 0, 0, 0);
                __syncthreads();
            }
            short* dst = pass ? R.s.vst : R.s.kst;
            #pragma unroll
            for (int mi = 0; mi < 2; mi++)
              #pragma unroll
              for (int ni = 0; ni < 2; ni++)
                #pragma unroll
                for (int r = 0; r < 4; r++) {
                    int ol = wm + mi * 16 + quad * 4 + r;
                    int nl = wn + ni * 16 + lr;
                    float v = acc[mi][ni][r] + b_qkv[base + ol];
                    if (!pass) v = v > 0.f ? v + 1.f : __expf(v);   // elu(k)+1
                    dst[ol * 72 + nl] = f2bf(v);
                }
            __syncthreads();
            if (!pass) {
                // ksum partial: 4 threads per d, shfl-reduce
                int d = t >> 2, nq = (t & 3) * 16;
                float s = 0.f;
                #pragma unroll
                for (int j = 0; j < 16; j++) s += bf2f(R.s.kst[d * 72 + nq + j]);
                s += __shfl_down(s, 2);
                s += __shfl_down(s, 1);
                if ((t & 3) == 0) ksp[((size_t)(b * 4 + h) * 64 + nt) * 64 + d] = s;
            }
        }
        // kv^T partial: A = vst rows (e), B = kst rows (d), K = 64 n
        f32x4 acc2[4] = {};
        #pragma unroll
        for (int kk = 0; kk < 64; kk += 32) {
            bf16x8 af = *(const bf16x8*)(R.s.vst + (wv * 16 + lr) * 72 + kk + quad * 8);
            bf16x8 bfk[4];
            #pragma unroll
            for (int ni = 0; ni < 4; ni++)
                bfk[ni] = *(const bf16x8*)(R.s.kst + (ni * 16 + lr) * 72 + kk + quad * 8);
            #pragma unroll
            for (int ni = 0; ni < 4; ni++)
                acc2[ni] = __builtin_amdgcn_mfma_f32_16x16x32_bf16(af, bfk[ni], acc2[ni], 0, 0, 0);
        }
        float* kvdst = kvp + ((size_t)(b * 4 + h) * 64 + nt) * 4096;
        #pragma unroll
        for (int ni = 0; ni < 4; ni++)
            #pragma unroll
            for (int r = 0; r < 4; r++)
                kvdst[(wv * 16 + quad * 4 + r) * 64 + ni * 16 + lr] = acc2[ni][r];
    }

    // ---- q GEMMs (128 rows each) ----
    for (int mtq = 0; mtq < 2; mtq++) {
        f32x4 acc[4][2] = {};
        int wm = (wv & 1) * 64, wn = (wv >> 1) * 32;
        for (int k0 = 0; k0 < 256; k0 += 32) {
            #pragma unroll
            for (int i = 0; i < 2; i++) {
                int ch = t + i * 256;
                int row = ch >> 2, kc = (ch & 3) * 8;
                *(u32x4*)(Asm + row * 40 + kc) = *(const u32x4*)(wq_bf + (size_t)(mtq * 128 + row) * 256 + k0 + kc);
            }
            __syncthreads();
            bf16x8 afr[4], bfr[2];
            #pragma unroll
            for (int mi = 0; mi < 4; mi++) afr[mi] = *(const bf16x8*)(Asm + (wm + mi * 16 + lr) * 40 + quad * 8);
            #pragma unroll
            for (int ni = 0; ni < 2; ni++) {
                int rr = wn + ni * 16 + lr;
                bfr[ni] = *(const bf16x8*)(Blds + rr * 264 + ((k0 + quad * 8) ^ (((rr >> 4) & 3) << 3)));
            }
            #pragma unroll
            for (int mi = 0; mi < 4; mi++)
                #pragma unroll
                for (int ni = 0; ni < 2; ni++)
                    acc[mi][ni] = __builtin_amdgcn_mfma_f32_16x16x32_bf16(afr[mi], bfr[ni], acc[mi][ni], 0, 0, 0);
            __syncthreads();
        }
        #pragma unroll
        for (int mi = 0; mi < 4; mi++)
          #pragma unroll
          for (int ni = 0; ni < 2; ni++)
            #pragma unroll
            for (int r = 0; r < 4; r++) {
                int ol = wm + mi * 16 + quad * 4 + r;
                int nl = wn + ni * 16 + lr;
                float v = acc[mi][ni][r] + b_qkv[mtq * 128 + ol];
                v = v > 0.f ? v + 1.f : __expf(v);              // elu(q)+1
                R.cst[nl * 136 + ol] = f2bf(v);
            }
        __syncthreads();
        #pragma unroll
        for (int i = 0; i < 4; i++) {
            int ch = t + i * 256;
            int row = ch >> 4, o8 = (ch & 15) * 8;
            int hh = mtq * 2 + (o8 >> 6), d0 = o8 & 63;
            *(u32x4*)(q_t + ((size_t)(b * 4 + hh) * NSP + n0 + row) * HD + d0) =
                *(const u32x4*)(R.cst + row * 136 + o8);
        }
        __syncthreads();
    }
}

// ---------------- reduce kv/ksum partials ----------------
__global__ __launch_bounds__(256) void k_kv_reduce(
        const float* __restrict__ kvp, const float* __restrict__ ksp,
        float* __restrict__ kvT_g, float* __restrict__ ksum_g) {
    int eq = blockIdx.x, bh = blockIdx.y;
    int t = threadIdx.x;
    const float* base = kvp + (size_t)bh * 64 * 4096 + eq * 1024;
    float4 s = {0.f, 0.f, 0.f, 0.f};
    for (int ntc = 0; ntc < 64; ntc++) {
        float4 v = *(const float4*)(base + (size_t)ntc * 4096 + t * 4);
        s.x += v.x; s.y += v.y; s.z += v.z; s.w += v.w;
    }
    *(float4*)(kvT_g + (size_t)bh * 4096 + eq * 1024 + t * 4) = s;
    if (eq == 0 && t < 64) {
        float ss = 0.f;
        for (int ntc = 0; ntc < 64; ntc++) ss += ksp[((size_t)bh * 64 + ntc) * 64 + t];
        ksum_g[bh * 64 + t] = ss;
    }
}

// ---------------- fused attention + out-projection + residual ----------------
// One block per (b, 64-n tile): per h, attn tile -> Battn[64n][256e]; then
// out[256o][64n] = Wout . Battn^T + b_out + x.
__global__ __launch_bounds__(256) void k_attn_out(
        const short* __restrict__ q_t, const float* __restrict__ kvT_g,
        const float* __restrict__ ksum_g, const short* __restrict__ wo_bf,
        const float* __restrict__ b_out, const float* __restrict__ x,
        float* __restrict__ out) {
    int b = blockIdx.y, nt = blockIdx.x;
    int n0 = nt * 64;
    __shared__ short Battn[64 * 264];
    __shared__ union UR {
        struct { short ql[64 * 72]; short kvl[64 * 72]; } a;
        short Asm2[128 * 40];
    } R;
    __shared__ float ksl[64], dnl[64];
    int t = threadIdx.x, lane = t & 63, wv = t >> 6, lr = lane & 15, quad = lane >> 4;

    for (int h = 0; h < 4; h++) {
        int bh = b * 4 + h;
        #pragma unroll
        for (int i = 0; i < 2; i++) {
            int ch = t + i * 256;
            int row = ch >> 3, dc = (ch & 7) * 8;
            *(u32x4*)(R.a.ql + row * 72 + dc) =
                *(const u32x4*)(q_t + ((size_t)bh * NSP + n0 + row) * HD + dc);
        }
        const float* kvg = kvT_g + (size_t)bh * 4096;
        for (int i = t; i < 4096; i += 256)
            R.a.kvl[(i >> 6) * 72 + (i & 63)] = f2bf(kvg[i]);
        if (t < 64) ksl[t] = ksum_g[bh * 64 + t];
        __syncthreads();
        if (t < 64) {
            float s = 0.f;
            #pragma unroll
            for (int d = 0; d < 64; d++) s += bf2f(R.a.ql[t * 72 + d]) * ksl[d];
            dnl[t] = 1.f / (s + 1e-6f);
        }
        __syncthreads();
        f32x4 acc[4] = {};
        #pragma unroll
        for (int kk = 0; kk < 64; kk += 32) {
            bf16x8 af = *(const bf16x8*)(R.a.ql + (wv * 16 + lr) * 72 + kk + quad * 8);
            bf16x8 bfr[4];
            #pragma unroll
            for (int ni = 0; ni < 4; ni++)
                bfr[ni] = *(const bf16x8*)(R.a.kvl + (ni * 16 + lr) * 72 + kk + quad * 8);
            #pragma unroll
            for (int ni = 0; ni < 4; ni++)
                acc[ni] = __builtin_amdgcn_mfma_f32_16x16x32_bf16(af, bfr[ni], acc[ni], 0, 0, 0);
        }
        float dn[4];
        #pragma unroll
        for (int r = 0; r < 4; r++) dn[r] = dnl[wv * 16 + quad * 4 + r];
        #pragma unroll
        for (int ni = 0; ni < 4; ni++)
            #pragma unroll
            for (int r = 0; r < 4; r++) {
                int n = wv * 16 + quad * 4 + r;
                int e = ni * 16 + lr;
                Battn[n * 264 + h * 64 + e] = f2bf(acc[ni][r] * dn[r]);
            }
        __syncthreads();
    }

    // out GEMM: two passes of 128 o
    for (int p = 0; p < 2; p++) {
        f32x4 acc[4][2] = {};
        int wm = (wv & 1) * 64, wn = (wv >> 1) * 32;
        for (int k0 = 0; k0 < 256; k0 += 32) {
            #pragma unroll
            for (int i = 0; i < 2; i++) {
                int ch = t + i * 256;
                int row = ch >> 2, kc = (ch & 3) * 8;
                *(u32x4*)(R.Asm2 + row * 40 + kc) =
                    *(const u32x4*)(wo_bf + (size_t)(p * 128 + row) * 256 + k0 + kc);
            }
            __syncthreads();
            bf16x8 afr[4], bfr[2];
            #pragma unroll
            for (int mi = 0; mi < 4; mi++) afr[mi] = *(const bf16x8*)(R.Asm2 + (wm + mi * 16 + lr) * 40 + quad * 8);
            #pragma unroll
            for (int ni = 0; ni < 2; ni++)
                bfr[ni] = *(const bf16x8*)(Battn + (wn + ni * 16 + lr) * 264 + k0 + quad * 8);
            #pragma unroll
            for (int mi = 0; mi < 4; mi++)
                #pragma unroll
                for (int ni = 0; ni < 2; ni++)
                    acc[mi][ni] = __builtin_amdgcn_mfma_f32_16x16x32_bf16(afr[mi], bfr[ni], acc[mi][ni], 0, 0, 0);
            __syncthreads();
        }
        #pragma unroll
        for (int mi = 0; mi < 4; mi++)
          #pragma unroll
          for (int ni = 0; ni < 2; ni++)
            #pragma unroll
            for (int r = 0; r < 4; r++) {
                int ol = wm + mi * 16 + quad * 4 + r;
                int nl = wn + ni * 16 + lr;
                int o = p * 128 + ol;
                size_t idx = ((size_t)b * CH + o) * NSP + n0 + nl;
                out[idx] = acc[mi][ni][r] + b_out[o] + x[idx];
            }
    }
}

extern "C" void kernel_launch(void* const* d_in, const int* in_sizes, int n_in,
                              void* d_out, int out_size, void* d_ws, size_t ws_size,
                              hipStream_t stream) {
    const float* x     = (const float*)d_in[0];
    const float* gamma = (const float*)d_in[1];
    const float* beta  = (const float*)d_in[2];
    const float* w_qkv = (const float*)d_in[3];
    const float* b_qkv = (const float*)d_in[4];
    const float* w_out = (const float*)d_in[5];
    const float* b_out = (const float*)d_in[6];
    float* out = (float*)d_out;

    char* ws = (char*)d_ws;
    size_t off = 0;
    float* mu    = (float*)(ws + off); off += 2048;
    float* rstd  = (float*)(ws + off); off += 2048;
    short* wq_bf = (short*)(ws + off); off += (size_t)768 * 256 * 2;
    short* wo_bf = (short*)(ws + off); off += (size_t)256 * 256 * 2;
    short* q_t   = (short*)(ws + off); off += (size_t)BATCH * NSP * CH * 2;   // [b][h][n][d]
    float* kvp   = (float*)(ws + off); off += (size_t)64 * 64 * 4096 * 4;     // [bh][nt64][e][d]
    float* ksp   = (float*)(ws + off); off += (size_t)64 * 64 * 64 * 4;       // [bh][nt64][d]
    float* kvT_g = (float*)(ws + off); off += (size_t)64 * 4096 * 4;          // [bh][e][d]
    float* ksum_g = (float*)(ws + off); off += (size_t)64 * 64 * 4;           // [bh][d]

    if (ws_size < off) return;

    k_pre<<<768, 256, 0, stream>>>(x, w_qkv, w_out, mu, rstd, wq_bf, wo_bf);
    k_gnqkv<<<dim3(64, 16), 256, 0, stream>>>(x, gamma, beta, mu, rstd, wq_bf, b_qkv, q_t, kvp, ksp);
    k_kv_reduce<<<dim3(4, 64), 256, 0, stream>>>(kvp, ksp, kvT_g, ksum_g);
    k_attn_out<<<dim3(64, 16), 256, 0, stream>>>(q_t, kvT_g, ksum_g, wo_bf, b_out, x, out);
}

// Round 5
// 259.739 us; speedup vs baseline: 1.2260x; 1.0902x over previous
//
#include <hip/hip_runtime.h>
#include <stdint.h>

#define BATCH 16
#define CH    256
#define NSP   4096   // 64*64 spatial
#define NH    4
#define HD    64

typedef __attribute__((ext_vector_type(8))) short bf16x8;
typedef __attribute__((ext_vector_type(4))) float f32x4;
typedef __attribute__((ext_vector_type(4))) unsigned int u32x4;

__device__ __forceinline__ short f2bf(float f) {
    union { float f; unsigned u; } v; v.f = f;
    unsigned r = (v.u + 0x7fffu + ((v.u >> 16) & 1u)) >> 16;
    return (short)r;
}
__device__ __forceinline__ float bf2f(short s) {
    union { float f; unsigned u; } v; v.u = ((unsigned)(unsigned short)s) << 16;
    return v.f;
}

// ---------------- fused: GN stats (blocks 0..511) + weight bf16 convert (512..767) ----------------
__global__ __launch_bounds__(256) void k_pre(
        const float* __restrict__ x, const float* __restrict__ wq, const float* __restrict__ wo,
        float* __restrict__ mu, float* __restrict__ rstd,
        short* __restrict__ wq_bf, short* __restrict__ wo_bf) {
    int bg = blockIdx.x;
    if (bg < 512) {
        const float4* p = (const float4*)(x + (size_t)bg * 32768);
        float s = 0.f, sq = 0.f;
        for (int i = threadIdx.x; i < 8192; i += 256) {
            float4 v = p[i];
            s  += v.x + v.y + v.z + v.w;
            sq += v.x * v.x + v.y * v.y + v.z * v.z + v.w * v.w;
        }
        for (int off = 32; off; off >>= 1) { s += __shfl_down(s, off); sq += __shfl_down(sq, off); }
        __shared__ float ls[4], lq[4];
        int w = threadIdx.x >> 6;
        if ((threadIdx.x & 63) == 0) { ls[w] = s; lq[w] = sq; }
        __syncthreads();
        if (threadIdx.x == 0) {
            float S = ls[0] + ls[1] + ls[2] + ls[3];
            float Q = lq[0] + lq[1] + lq[2] + lq[3];
            float m = S / 32768.f;
            float var = Q / 32768.f - m * m;
            mu[bg] = m; rstd[bg] = rsqrtf(var + 1e-5f);
        }
    } else {
        int idx = ((bg - 512) * 256 + threadIdx.x) * 4;
        float4 v;
        short* dst;
        if (idx < 196608) { v = *(const float4*)(wq + idx); dst = wq_bf + idx; }
        else              { v = *(const float4*)(wo + (idx - 196608)); dst = wo_bf + (idx - 196608); }
        unsigned p0 = ((unsigned)(unsigned short)f2bf(v.x)) | (((unsigned)(unsigned short)f2bf(v.y)) << 16);
        unsigned p1 = ((unsigned)(unsigned short)f2bf(v.z)) | (((unsigned)(unsigned short)f2bf(v.w)) << 16);
        uint2 pk; pk.x = p0; pk.y = p1;
        *(uint2*)dst = pk;
    }
}

// ---------------- fused GN-apply + QKV + kv^T/ksum partials + q_t ----------------
// One block per (b, 64-n tile). B-tile (xn^T, [n][c]) built once in LDS (GN applied,
// XOR bank-swizzle). A fragments come DIRECTLY from global (weights are L2-resident)
// -> the K-loops contain no __syncthreads at all.
// 4 head-passes: waves 0-1 compute k_h (elu+1), waves 2-3 compute v_h; stage [d|e][n]
// in LDS; kv-MFMA -> bf16 partial; ksum partial.
// 2 q-passes (128 rows each): elu+1, LDS transpose, q_t[b][h][n][d].
__global__ __launch_bounds__(256) void k_gnqkv(
        const float* __restrict__ x, const float* __restrict__ gamma, const float* __restrict__ beta,
        const float* __restrict__ mu, const float* __restrict__ rstd,
        const short* __restrict__ wq_bf, const float* __restrict__ b_qkv,
        short* __restrict__ q_t, short* __restrict__ kvp_bf, float* __restrict__ ksp) {
    int b = blockIdx.y, nt = blockIdx.x;
    int n0 = nt * 64;
    __shared__ short Blds[64 * 264];          // [n][c^swz]
    __shared__ union UR {
        struct { short kst[64 * 72]; short vst[64 * 72]; } s;
        short cst[64 * 136];
    } R;
    int t = threadIdx.x, lane = t & 63, wv = t >> 6, lr = lane & 15, quad = lane >> 4;

    // ---- build B tile with GN ----
    {
        const float* xb = x + (size_t)b * CH * NSP;
        int m = t & 15, cq = t >> 4;
        for (int cb = 0; cb < 16; cb++) {
            int c = cb * 16 + cq;
            int g = c >> 3;
            float sc = rstd[b * 32 + g] * gamma[c];
            float sh = beta[c] - mu[b * 32 + g] * sc;
            float4 v = *(const float4*)(xb + (size_t)c * NSP + n0 + m * 4);
            float vv[4] = {v.x, v.y, v.z, v.w};
            #pragma unroll
            for (int j = 0; j < 4; j++) {
                int n = m * 4 + j;
                int cc = c ^ (((n >> 4) & 3) << 3);
                Blds[n * 264 + cc] = f2bf(vv[j] * sc + sh);
            }
        }
    }
    __syncthreads();

    // ---- per-head k/v + kv partial ----
    for (int h = 0; h < 4; h++) {
        int base_row = (wv < 2 ? 256 : 512) + h * 64;   // k rows for waves 0-1, v rows for 2-3
        int sub = (wv & 1) * 32;
        f32x4 acc[2][4] = {};
        for (int k0 = 0; k0 < 256; k0 += 32) {          // barrier-free K-loop
            bf16x8 afr[2], bfr[4];
            #pragma unroll
            for (int mi = 0; mi < 2; mi++)
                afr[mi] = *(const bf16x8*)(wq_bf + (size_t)(base_row + sub + mi * 16 + lr) * 256 + k0 + quad * 8);
            #pragma unroll
            for (int ni = 0; ni < 4; ni++) {
                int rr = ni * 16 + lr;
                bfr[ni] = *(const bf16x8*)(Blds + rr * 264 + ((k0 + quad * 8) ^ (((rr >> 4) & 3) << 3)));
            }
            #pragma unroll
            for (int mi = 0; mi < 2; mi++)
                #pragma unroll
                for (int ni = 0; ni < 4; ni++)
                    acc[mi][ni] = __builtin_amdgcn_mfma_f32_16x16x32_bf16(afr[mi], bfr[ni], acc[mi][ni], 0, 0, 0);
        }
        __syncthreads();   // protect R reuse from previous pass
        short* dst = (wv < 2) ? R.s.kst : R.s.vst;
        bool is_k = (wv < 2);
        #pragma unroll
        for (int mi = 0; mi < 2; mi++)
          #pragma unroll
          for (int ni = 0; ni < 4; ni++)
            #pragma unroll
            for (int r = 0; r < 4; r++) {
                int ol = sub + mi * 16 + quad * 4 + r;   // 0..63
                int nl = ni * 16 + lr;
                float v = acc[mi][ni][r] + b_qkv[base_row + ol];
                if (is_k) v = v > 0.f ? v + 1.f : __expf(v);   // elu(k)+1
                dst[ol * 72 + nl] = f2bf(v);
            }
        __syncthreads();
        // ksum partial
        {
            int d = t >> 2, nq = (t & 3) * 16;
            float s = 0.f;
            #pragma unroll
            for (int j = 0; j < 16; j++) s += bf2f(R.s.kst[d * 72 + nq + j]);
            s += __shfl_down(s, 2);
            s += __shfl_down(s, 1);
            if ((t & 3) == 0) ksp[((size_t)(b * 4 + h) * 64 + nt) * 64 + d] = s;
        }
        // kv^T partial: A = vst (e rows), B = kst (d rows), K = 64 n
        f32x4 acc2[4] = {};
        #pragma unroll
        for (int kk = 0; kk < 64; kk += 32) {
            bf16x8 af = *(const bf16x8*)(R.s.vst + (wv * 16 + lr) * 72 + kk + quad * 8);
            bf16x8 bfk[4];
            #pragma unroll
            for (int ni = 0; ni < 4; ni++)
                bfk[ni] = *(const bf16x8*)(R.s.kst + (ni * 16 + lr) * 72 + kk + quad * 8);
            #pragma unroll
            for (int ni = 0; ni < 4; ni++)
                acc2[ni] = __builtin_amdgcn_mfma_f32_16x16x32_bf16(af, bfk[ni], acc2[ni], 0, 0, 0);
        }
        short* kvdst = kvp_bf + ((size_t)(b * 4 + h) * 64 + nt) * 4096;
        #pragma unroll
        for (int ni = 0; ni < 4; ni++)
            #pragma unroll
            for (int r = 0; r < 4; r++)
                kvdst[(wv * 16 + quad * 4 + r) * 64 + ni * 16 + lr] = f2bf(acc2[ni][r]);
    }

    // ---- q passes (128 rows each), barrier-free K-loop ----
    for (int mtq = 0; mtq < 2; mtq++) {
        f32x4 acc[2][4] = {};
        int wm = wv * 32;
        for (int k0 = 0; k0 < 256; k0 += 32) {
            bf16x8 afr[2], bfr[4];
            #pragma unroll
            for (int mi = 0; mi < 2; mi++)
                afr[mi] = *(const bf16x8*)(wq_bf + (size_t)(mtq * 128 + wm + mi * 16 + lr) * 256 + k0 + quad * 8);
            #pragma unroll
            for (int ni = 0; ni < 4; ni++) {
                int rr = ni * 16 + lr;
                bfr[ni] = *(const bf16x8*)(Blds + rr * 264 + ((k0 + quad * 8) ^ (((rr >> 4) & 3) << 3)));
            }
            #pragma unroll
            for (int mi = 0; mi < 2; mi++)
                #pragma unroll
                for (int ni = 0; ni < 4; ni++)
                    acc[mi][ni] = __builtin_amdgcn_mfma_f32_16x16x32_bf16(afr[mi], bfr[ni], acc[mi][ni], 0, 0, 0);
        }
        __syncthreads();   // protect cst reuse
        #pragma unroll
        for (int mi = 0; mi < 2; mi++)
          #pragma unroll
          for (int ni = 0; ni < 4; ni++)
            #pragma unroll
            for (int r = 0; r < 4; r++) {
                int ol = wm + mi * 16 + quad * 4 + r;    // 0..127
                int nl = ni * 16 + lr;
                float v = acc[mi][ni][r] + b_qkv[mtq * 128 + ol];
                v = v > 0.f ? v + 1.f : __expf(v);       // elu(q)+1
                R.cst[nl * 136 + ol] = f2bf(v);
            }
        __syncthreads();
        #pragma unroll
        for (int i = 0; i < 4; i++) {
            int ch = t + i * 256;
            int row = ch >> 4, o8 = (ch & 15) * 8;
            int hh = mtq * 2 + (o8 >> 6), d0 = o8 & 63;
            *(u32x4*)(q_t + ((size_t)(b * 4 + hh) * NSP + n0 + row) * HD + d0) =
                *(const u32x4*)(R.cst + row * 136 + o8);
        }
    }
}

// ---------------- reduce bf16 kv partials -> bf16 kvT; fp32 ksum ----------------
__global__ __launch_bounds__(256) void k_kv_reduce(
        const short* __restrict__ kvp_bf, const float* __restrict__ ksp,
        short* __restrict__ kvT_bf, float* __restrict__ ksum_g) {
    int p = blockIdx.x, bh = blockIdx.y;
    int t = threadIdx.x;
    int chunk = p * 256 + t;                 // 0..511, 8 elems each
    const short* base = kvp_bf + (size_t)bh * 64 * 4096 + chunk * 8;
    float s[8] = {};
    for (int ntc = 0; ntc < 64; ntc++) {
        bf16x8 v = *(const bf16x8*)(base + (size_t)ntc * 4096);
        #pragma unroll
        for (int j = 0; j < 8; j++) s[j] += bf2f(v[j]);
    }
    bf16x8 rv;
    #pragma unroll
    for (int j = 0; j < 8; j++) rv[j] = f2bf(s[j]);
    *(bf16x8*)(kvT_bf + (size_t)bh * 4096 + chunk * 8) = rv;
    if (p == 0 && t < 64) {
        float ss = 0.f;
        for (int ntc = 0; ntc < 64; ntc++) ss += ksp[((size_t)bh * 64 + ntc) * 64 + t];
        ksum_g[bh * 64 + t] = ss;
    }
}

// ---------------- fused attention + out-projection + residual ----------------
// One block per (b, 64-n tile). Per head: attn -> Battn[64n][256e] (denom-scaled);
// then out GEMM with A = Wout direct from global (barrier-free K-loop) + bias + residual.
__global__ __launch_bounds__(256) void k_attn_out(
        const short* __restrict__ q_t, const short* __restrict__ kvT_bf,
        const float* __restrict__ ksum_g, const short* __restrict__ wo_bf,
        const float* __restrict__ b_out, const float* __restrict__ x,
        float* __restrict__ out) {
    int b = blockIdx.y, nt = blockIdx.x;
    int n0 = nt * 64;
    __shared__ short Battn[64 * 264];
    __shared__ short ql[64 * 72];
    __shared__ short kvl[64 * 72];
    __shared__ float ksl[64], dnl[64];
    int t = threadIdx.x, lane = t & 63, wv = t >> 6, lr = lane & 15, quad = lane >> 4;

    for (int h = 0; h < 4; h++) {
        int bh = b * 4 + h;
        #pragma unroll
        for (int i = 0; i < 2; i++) {
            int ch = t + i * 256;
            int row = ch >> 3, dc = (ch & 7) * 8;
            *(u32x4*)(ql + row * 72 + dc) =
                *(const u32x4*)(q_t + ((size_t)bh * NSP + n0 + row) * HD + dc);
            *(u32x4*)(kvl + row * 72 + dc) =
                *(const u32x4*)(kvT_bf + (size_t)bh * 4096 + row * 64 + dc);
        }
        if (t < 64) ksl[t] = ksum_g[bh * 64 + t];
        __syncthreads();
        if (t < 64) {
            float s = 0.f;
            #pragma unroll
            for (int d = 0; d < 64; d++) s += bf2f(ql[t * 72 + d]) * ksl[d];
            dnl[t] = 1.f / (s + 1e-6f);
        }
        __syncthreads();
        f32x4 acc[4] = {};
        #pragma unroll
        for (int kk = 0; kk < 64; kk += 32) {
            bf16x8 af = *(const bf16x8*)(ql + (wv * 16 + lr) * 72 + kk + quad * 8);
            bf16x8 bfr[4];
            #pragma unroll
            for (int ni = 0; ni < 4; ni++)
                bfr[ni] = *(const bf16x8*)(kvl + (ni * 16 + lr) * 72 + kk + quad * 8);
            #pragma unroll
            for (int ni = 0; ni < 4; ni++)
                acc[ni] = __builtin_amdgcn_mfma_f32_16x16x32_bf16(af, bfr[ni], acc[ni], 0, 0, 0);
        }
        float dn[4];
        #pragma unroll
        for (int r = 0; r < 4; r++) dn[r] = dnl[wv * 16 + quad * 4 + r];
        #pragma unroll
        for (int ni = 0; ni < 4; ni++)
            #pragma unroll
            for (int r = 0; r < 4; r++) {
                int n = wv * 16 + quad * 4 + r;
                Battn[n * 264 + h * 64 + ni * 16 + lr] = f2bf(acc[ni][r] * dn[r]);
            }
        __syncthreads();
    }

    // out GEMM: 2 passes of 128 o, barrier-free K-loops
    for (int p = 0; p < 2; p++) {
        f32x4 acc[2][4] = {};
        int wm = wv * 32;
        for (int k0 = 0; k0 < 256; k0 += 32) {
            bf16x8 afr[2], bfr[4];
            #pragma unroll
            for (int mi = 0; mi < 2; mi++)
                afr[mi] = *(const bf16x8*)(wo_bf + (size_t)(p * 128 + wm + mi * 16 + lr) * 256 + k0 + quad * 8);
            #pragma unroll
            for (int ni = 0; ni < 4; ni++)
                bfr[ni] = *(const bf16x8*)(Battn + (ni * 16 + lr) * 264 + k0 + quad * 8);
            #pragma unroll
            for (int mi = 0; mi < 2; mi++)
                #pragma unroll
                for (int ni = 0; ni < 4; ni++)
                    acc[mi][ni] = __builtin_amdgcn_mfma_f32_16x16x32_bf16(afr[mi], bfr[ni], acc[mi][ni], 0, 0, 0);
        }
        #pragma unroll
        for (int mi = 0; mi < 2; mi++)
          #pragma unroll
          for (int ni = 0; ni < 4; ni++)
            #pragma unroll
            for (int r = 0; r < 4; r++) {
                int o = p * 128 + wm + mi * 16 + quad * 4 + r;
                int nl = ni * 16 + lr;
                size_t idx = ((size_t)b * CH + o) * NSP + n0 + nl;
                out[idx] = acc[mi][ni][r] + b_out[o] + x[idx];
            }
    }
}

extern "C" void kernel_launch(void* const* d_in, const int* in_sizes, int n_in,
                              void* d_out, int out_size, void* d_ws, size_t ws_size,
                              hipStream_t stream) {
    const float* x     = (const float*)d_in[0];
    const float* gamma = (const float*)d_in[1];
    const float* beta  = (const float*)d_in[2];
    const float* w_qkv = (const float*)d_in[3];
    const float* b_qkv = (const float*)d_in[4];
    const float* w_out = (const float*)d_in[5];
    const float* b_out = (const float*)d_in[6];
    float* out = (float*)d_out;

    char* ws = (char*)d_ws;
    size_t off = 0;
    float* mu     = (float*)(ws + off); off += 2048;
    float* rstd   = (float*)(ws + off); off += 2048;
    short* wq_bf  = (short*)(ws + off); off += (size_t)768 * 256 * 2;
    short* wo_bf  = (short*)(ws + off); off += (size_t)256 * 256 * 2;
    short* q_t    = (short*)(ws + off); off += (size_t)BATCH * NSP * CH * 2;   // [b][h][n][d]
    short* kvp_bf = (short*)(ws + off); off += (size_t)64 * 64 * 4096 * 2;     // [bh][nt64][e][d] bf16
    float* ksp    = (float*)(ws + off); off += (size_t)64 * 64 * 64 * 4;       // [bh][nt64][d]
    short* kvT_bf = (short*)(ws + off); off += (size_t)64 * 4096 * 2;          // [bh][e][d] bf16
    float* ksum_g = (float*)(ws + off); off += (size_t)64 * 64 * 4;            // [bh][d]

    if (ws_size < off) return;

    k_pre<<<768, 256, 0, stream>>>(x, w_qkv, w_out, mu, rstd, wq_bf, wo_bf);
    k_gnqkv<<<dim3(64, 16), 256, 0, stream>>>(x, gamma, beta, mu, rstd, wq_bf, b_qkv, q_t, kvp_bf, ksp);
    k_kv_reduce<<<dim3(2, 64), 256, 0, stream>>>(kvp_bf, ksp, kvT_bf, ksum_g);
    k_attn_out<<<dim3(64, 16), 256, 0, stream>>>(q_t, kvT_bf, ksum_g, wo_bf, b_out, x, out);
}